// Round 2
// 176.886 us; speedup vs baseline: 1.0169x; 1.0169x over previous
//
#include <hip/hip_runtime.h>

// GCN layer: out = A_norm @ (h @ W^T + b), A_norm = D^-1/2 (A + I) D^-1/2
// Inputs: h [N,128] f32, W [128,128] f32, b [128] f32, edges [2,E] int32
// Output: [N,128] f32
//
// R11b: CSR -> ELL (CAP=40, Poisson(16) tail => overflow ~never).
//      (1) count+fill collapse into ONE edge pass: pos = atomicAdd rank,
//          written directly into ell[dst*CAP+rank]; no scan, no rank array,
//          no second edge read. Overflow edges (rank>=CAP) go to a tiny
//          list drained by the owning node's half-wave inside k_agg.
//      (2) edge pass fused into the GEMM kernel (block-split) -- GEMM no
//          longer needs rs (normalization moved into k_agg as fma with
//          rsqrtf(cnt[s]+1); cnt is 200KB, L2-resident).
//      Pipeline: memset -> k_fused -> k_agg  (3 dispatches, was 6).
//      (R11 fix: ACCW macro param captured the .w member access -> inline fn.)

#define IN_DIM 128
#define OUT_DIM 128
#define CAP 40    // ELL capacity; P(deg>40 | lambda=16) ~ 3e-7
#define NEB 1024  // edge-pass blocks appended to the GEMM grid

typedef short bf16x8 __attribute__((ext_vector_type(8)));
typedef float f32x4 __attribute__((ext_vector_type(4)));

__device__ __forceinline__ unsigned short f2bf(float f) {
    unsigned u = __float_as_uint(f);
    u += 0x7fffu + ((u >> 16) & 1u);  // round-nearest-even
    return (unsigned short)(u >> 16);
}
__device__ __forceinline__ float bf2f(unsigned short s) {
    return __uint_as_float(((unsigned)s) << 16);
}
__device__ __forceinline__ void accw(float4& acc, ushort4 v, float wt) {
    acc.x += wt * bf2f(v.x);
    acc.y += wt * bf2f(v.y);
    acc.z += wt * bf2f(v.z);
    acc.w += wt * bf2f(v.w);
}

// Fused: blocks [0,nlin) compute hs = h@W^T + b (bf16, UNscaled) via MFMA;
// blocks [nlin, nlin+NEB) do the single-pass ELL build:
//   r = atomicAdd(&cnt[d],1); r<CAP ? ell[d*CAP+r]=s : overflow-append.
__global__ __launch_bounds__(256) void k_fused(
        const float* __restrict__ h, const float* __restrict__ W,
        const float* __restrict__ b, unsigned short* __restrict__ hsb, int n,
        const int* __restrict__ ed, int* __restrict__ cnt,
        int* __restrict__ ell, int2* __restrict__ ovf, int E, int nlin) {
    __shared__ unsigned short sA[128 * 136];  // h tile bf16 (+8 pad)
    __shared__ unsigned short sB[128 * 136];  // W bf16 [n][k]

    if ((int)blockIdx.x >= nlin) {
        // ---- single-pass ELL fill ----
        int fb = blockIdx.x - nlin;
        int chunk = (E + NEB - 1) / NEB;
        int e1 = min(E, fb * chunk + chunk);
        for (int e = fb * chunk + threadIdx.x; e < e1; e += 256) {
            int s = ed[e];
            int d = ed[E + e];
            int r = atomicAdd(&cnt[d], 1);
            if (r < CAP) {
                ell[(size_t)d * CAP + r] = s;
            } else {
                int k = atomicAdd(&cnt[n], 1);  // cnt[n] = overflow counter
                ovf[k] = make_int2(s, d);
            }
        }
        return;
    }

    // ---- MFMA linear: 128x128 tile, K=128, 4 waves ----
    const int tid = threadIdx.x;
    const int lane = tid & 63;
    const int wv = tid >> 6;
    const int quad = lane >> 4;
    const int l16 = lane & 15;
    const int row0 = blockIdx.x * 128;

    {
        const float4* h4 = (const float4*)h;
        const float4* W4 = (const float4*)W;
        for (int t = tid; t < 128 * 32; t += 256) {
            int r = t >> 5, c4 = t & 31;
            int row = row0 + r;
            float4 v = make_float4(0.f, 0.f, 0.f, 0.f);
            if (row < n) v = h4[(size_t)row * 32 + c4];
            ushort4 p;
            p.x = f2bf(v.x); p.y = f2bf(v.y); p.z = f2bf(v.z); p.w = f2bf(v.w);
            ((ushort4*)sA)[r * 34 + c4] = p;  // 136/4 = 34
            float4 w = W4[t];
            ushort4 q;
            q.x = f2bf(w.x); q.y = f2bf(w.y); q.z = f2bf(w.z); q.w = f2bf(w.w);
            ((ushort4*)sB)[r * 34 + c4] = q;
        }
    }
    __syncthreads();

    f32x4 acc[2][8];
#pragma unroll
    for (int mt = 0; mt < 2; ++mt)
#pragma unroll
        for (int nt = 0; nt < 8; ++nt) acc[mt][nt] = (f32x4){0.f, 0.f, 0.f, 0.f};

    const int koff = quad * 8;
#pragma unroll
    for (int kc = 0; kc < 4; ++kc) {
        int kbase = kc * 32 + koff;
        bf16x8 a0 = *(const bf16x8*)(sA + (wv * 32 + 0 + l16) * 136 + kbase);
        bf16x8 a1 = *(const bf16x8*)(sA + (wv * 32 + 16 + l16) * 136 + kbase);
#pragma unroll
        for (int nt = 0; nt < 8; ++nt) {
            bf16x8 bb = *(const bf16x8*)(sB + (nt * 16 + l16) * 136 + kbase);
            acc[0][nt] = __builtin_amdgcn_mfma_f32_16x16x32_bf16(a0, bb, acc[0][nt], 0, 0, 0);
            acc[1][nt] = __builtin_amdgcn_mfma_f32_16x16x32_bf16(a1, bb, acc[1][nt], 0, 0, 0);
        }
    }

    // epilogue: bias, bf16 store (no rs scaling here anymore)
#pragma unroll
    for (int mt = 0; mt < 2; ++mt) {
#pragma unroll
        for (int r = 0; r < 4; ++r) {
            int row = row0 + wv * 32 + mt * 16 + quad * 4 + r;
            if (row >= n) continue;
#pragma unroll
            for (int nt = 0; nt < 8; ++nt) {
                int col = nt * 16 + l16;
                hsb[(size_t)row * 128 + col] = f2bf(acc[mt][nt][r] + b[col]);
            }
        }
    }
}

// Half-wave (32 lanes) per node; lane = 4 channels (ushort4 = 8B).
// out[d] = rs_d * ( rs_d*hs[d] + sum_{s in N(d)} rs_s*hs[s] ),
// rs_x = rsqrt(cnt[x]+1) computed on the fly (cnt is L2-resident).
__global__ __launch_bounds__(256) void k_agg(const int* __restrict__ cnt,
                                             const int* __restrict__ ell,
                                             const int2* __restrict__ ovf,
                                             const unsigned short* __restrict__ hsb,
                                             float* __restrict__ out, int n) {
    int node = blockIdx.x * 8 + (threadIdx.x >> 5);
    if (node >= n) return;
    int lane = threadIdx.x & 31;
    int deg = cnt[node];
    float rsn = rsqrtf((float)(deg + 1));
    int m = min(deg, CAP);

    const ushort4* hp = (const ushort4*)hsb;  // row = 32 ushort4
    ushort4 sv = hp[(size_t)node * 32 + lane];
    float4 acc;
    acc.x = rsn * bf2f(sv.x); acc.y = rsn * bf2f(sv.y);
    acc.z = rsn * bf2f(sv.z); acc.w = rsn * bf2f(sv.w);

    const int4* row4 = (const int4*)(ell + (size_t)node * CAP);  // CAP*4=160B, 16B-aligned
    int e = 0;
    for (; e + 8 <= m; e += 8) {  // 2 int4 index loads + 8 cnt + 8 row gathers in flight
        int4 p0 = row4[(e >> 2) + 0];
        int4 p1 = row4[(e >> 2) + 1];
        int c0 = cnt[p0.x], c1 = cnt[p0.y], c2 = cnt[p0.z], c3 = cnt[p0.w];
        int c4 = cnt[p1.x], c5 = cnt[p1.y], c6 = cnt[p1.z], c7 = cnt[p1.w];
        ushort4 v0 = hp[(size_t)p0.x * 32 + lane];
        ushort4 v1 = hp[(size_t)p0.y * 32 + lane];
        ushort4 v2 = hp[(size_t)p0.z * 32 + lane];
        ushort4 v3 = hp[(size_t)p0.w * 32 + lane];
        ushort4 v4 = hp[(size_t)p1.x * 32 + lane];
        ushort4 v5 = hp[(size_t)p1.y * 32 + lane];
        ushort4 v6 = hp[(size_t)p1.z * 32 + lane];
        ushort4 v7 = hp[(size_t)p1.w * 32 + lane];
        float w0 = rsqrtf((float)(c0 + 1)), w1 = rsqrtf((float)(c1 + 1));
        float w2 = rsqrtf((float)(c2 + 1)), w3 = rsqrtf((float)(c3 + 1));
        float w4 = rsqrtf((float)(c4 + 1)), w5 = rsqrtf((float)(c5 + 1));
        float w6 = rsqrtf((float)(c6 + 1)), w7 = rsqrtf((float)(c7 + 1));
        accw(acc, v0, w0); accw(acc, v1, w1); accw(acc, v2, w2); accw(acc, v3, w3);
        accw(acc, v4, w4); accw(acc, v5, w5); accw(acc, v6, w6); accw(acc, v7, w7);
    }
    if (e + 4 <= m) {
        int4 p0 = row4[e >> 2];
        int c0 = cnt[p0.x], c1 = cnt[p0.y], c2 = cnt[p0.z], c3 = cnt[p0.w];
        ushort4 v0 = hp[(size_t)p0.x * 32 + lane];
        ushort4 v1 = hp[(size_t)p0.y * 32 + lane];
        ushort4 v2 = hp[(size_t)p0.z * 32 + lane];
        ushort4 v3 = hp[(size_t)p0.w * 32 + lane];
        float w0 = rsqrtf((float)(c0 + 1)), w1 = rsqrtf((float)(c1 + 1));
        float w2 = rsqrtf((float)(c2 + 1)), w3 = rsqrtf((float)(c3 + 1));
        accw(acc, v0, w0); accw(acc, v1, w1); accw(acc, v2, w2); accw(acc, v3, w3);
        e += 4;
    }
    for (; e < m; ++e) {
        int s = ell[(size_t)node * CAP + e];
        float wt = rsqrtf((float)(cnt[s] + 1));
        ushort4 v = hp[(size_t)s * 32 + lane];
        accw(acc, v, wt);
    }
    if (deg > CAP) {  // expect: never taken (P ~ 3e-7 per node)
        int novf = cnt[n];
        for (int i = 0; i < novf; ++i) {
            int2 p = ovf[i];
            if (p.y == node) {
                float wt = rsqrtf((float)(cnt[p.x] + 1));
                ushort4 v = hp[(size_t)p.x * 32 + lane];
                accw(acc, v, wt);
            }
        }
    }
    acc.x *= rsn; acc.y *= rsn; acc.z *= rsn; acc.w *= rsn;
    ((float4*)out)[(size_t)node * 32 + lane] = acc;
}

extern "C" void kernel_launch(void* const* d_in, const int* in_sizes, int n_in,
                              void* d_out, int out_size, void* d_ws, size_t ws_size,
                              hipStream_t stream) {
    const float* h = (const float*)d_in[0];
    const float* W = (const float*)d_in[1];
    const float* b = (const float*)d_in[2];
    const int* edges = (const int*)d_in[3];

    const int n = in_sizes[0] / IN_DIM;  // 50000
    const int E = in_sizes[3] / 2;       // 800000
    const int nlin = (n + 127) / 128;    // 391 GEMM tiles

    // workspace carve-up (float units, each region 2KB-aligned)
    size_t o = 0;
    auto carve = [&](size_t elems) {
        size_t cur = o;
        o += (elems + 511) & ~(size_t)511;
        return cur;
    };
    float* ws = (float*)d_ws;
    unsigned short* hsb = (unsigned short*)(ws + carve((size_t)n * 64));  // n*128 bf16
    int*  cnt = (int*)(ws + carve(n + 1));          // [n]=degree counts, [n]=ovf counter
    int*  ell = (int*)(ws + carve((size_t)n * CAP));
    int2* ovf = (int2*)(ws + carve((size_t)E * 2));

    float* out = (float*)d_out;

    hipMemsetAsync(cnt, 0, (size_t)(n + 1) * sizeof(int), stream);
    k_fused<<<nlin + NEB, 256, 0, stream>>>(h, W, b, hsb, n, edges, cnt, ell, ovf, E, nlin);
    k_agg<<<(n + 7) / 8, 256, 0, stream>>>(cnt, ell, ovf, hsb, out, n);
}

// Round 3
// 174.600 us; speedup vs baseline: 1.0303x; 1.0131x over previous
//
#include <hip/hip_runtime.h>

// GCN layer: out = A_norm @ (h @ W^T + b), A_norm = D^-1/2 (A + I) D^-1/2
// Inputs: h [N,128] f32, W [128,128] f32, b [128] f32, edges [2,E] int32
// Output: [N,128] f32
//
// R12: un-fuse the ELL build (R11's fused fill ran at 8 waves/CU because the
//      GEMM's 68KB LDS is allocated for every block -> latency-bound, 70us).
//      (1) k_fill standalone, no LDS, 1 thread/edge -> 32 waves/CU.
//      (2) cnt padded to one counter per 64B line (CNT_STRIDE=16) -> kills
//          same-cacheline serialization of the 800K ticket atomics.
//      (3) ELL entries ushort (n<65536) -> halves scattered-write traffic.
//      (4) fill precedes GEMM -> GEMM epilogue applies rs = rsqrt(deg+1)
//          (reads padded cnt once per row); k_agg is now a pure gather-sum
//          (no per-edge cnt gather / rsqrt / weighted fma).
//      Pipeline: memset -> k_fill -> k_gemm -> k_agg.

#define IN_DIM 128
#define OUT_DIM 128
#define CAP 40         // ELL capacity; P(deg>40 | Poisson(16)) ~ 3e-7
#define CNT_STRIDE 16  // one int counter per 64B line

typedef short bf16x8 __attribute__((ext_vector_type(8)));
typedef float f32x4 __attribute__((ext_vector_type(4)));
typedef unsigned short us8 __attribute__((ext_vector_type(8)));
typedef unsigned short us4 __attribute__((ext_vector_type(4)));

__device__ __forceinline__ unsigned short f2bf(float f) {
    unsigned u = __float_as_uint(f);
    u += 0x7fffu + ((u >> 16) & 1u);  // round-nearest-even
    return (unsigned short)(u >> 16);
}
__device__ __forceinline__ float bf2f(unsigned short s) {
    return __uint_as_float(((unsigned)s) << 16);
}
__device__ __forceinline__ void acca(float4& acc, ushort4 v) {
    acc.x += bf2f(v.x);
    acc.y += bf2f(v.y);
    acc.z += bf2f(v.z);
    acc.w += bf2f(v.w);
}

// One thread per edge: ticket atomic on padded counter, direct ELL store.
__global__ __launch_bounds__(256) void k_fill(const int* __restrict__ ed,
                                              int* __restrict__ cnt,
                                              unsigned short* __restrict__ ell,
                                              int2* __restrict__ ovf, int E, int n) {
    int e = blockIdx.x * 256 + threadIdx.x;
    if (e >= E) return;
    int s = ed[e];
    int d = ed[E + e];
    int r = atomicAdd(&cnt[(size_t)d * CNT_STRIDE], 1);
    if (r < CAP) {
        ell[(size_t)d * CAP + r] = (unsigned short)s;
    } else {
        int k = atomicAdd(&cnt[(size_t)n * CNT_STRIDE], 1);  // overflow counter
        ovf[k] = make_int2(s, d);
    }
}

// MFMA linear: hs[row] = bf16( (h@W^T + b)[row] * rsqrt(deg[row]+1) ).
__global__ __launch_bounds__(256) void k_gemm(
        const float* __restrict__ h, const float* __restrict__ W,
        const float* __restrict__ b, const int* __restrict__ cnt,
        unsigned short* __restrict__ hsb, int n) {
    __shared__ unsigned short sA[128 * 136];  // h tile bf16 (+8 pad)
    __shared__ unsigned short sB[128 * 136];  // W bf16 [n][k]

    const int tid = threadIdx.x;
    const int lane = tid & 63;
    const int wv = tid >> 6;
    const int quad = lane >> 4;
    const int l16 = lane & 15;
    const int row0 = blockIdx.x * 128;

    {
        const float4* h4 = (const float4*)h;
        const float4* W4 = (const float4*)W;
        for (int t = tid; t < 128 * 32; t += 256) {
            int r = t >> 5, c4 = t & 31;
            int row = row0 + r;
            float4 v = make_float4(0.f, 0.f, 0.f, 0.f);
            if (row < n) v = h4[(size_t)row * 32 + c4];
            ushort4 p;
            p.x = f2bf(v.x); p.y = f2bf(v.y); p.z = f2bf(v.z); p.w = f2bf(v.w);
            ((ushort4*)sA)[r * 34 + c4] = p;  // 136/4 = 34
            float4 w = W4[t];
            ushort4 q;
            q.x = f2bf(w.x); q.y = f2bf(w.y); q.z = f2bf(w.z); q.w = f2bf(w.w);
            ((ushort4*)sB)[r * 34 + c4] = q;
        }
    }
    __syncthreads();

    f32x4 acc[2][8];
#pragma unroll
    for (int mt = 0; mt < 2; ++mt)
#pragma unroll
        for (int nt = 0; nt < 8; ++nt) acc[mt][nt] = (f32x4){0.f, 0.f, 0.f, 0.f};

    const int koff = quad * 8;
#pragma unroll
    for (int kc = 0; kc < 4; ++kc) {
        int kbase = kc * 32 + koff;
        bf16x8 a0 = *(const bf16x8*)(sA + (wv * 32 + 0 + l16) * 136 + kbase);
        bf16x8 a1 = *(const bf16x8*)(sA + (wv * 32 + 16 + l16) * 136 + kbase);
#pragma unroll
        for (int nt = 0; nt < 8; ++nt) {
            bf16x8 bb = *(const bf16x8*)(sB + (nt * 16 + l16) * 136 + kbase);
            acc[0][nt] = __builtin_amdgcn_mfma_f32_16x16x32_bf16(a0, bb, acc[0][nt], 0, 0, 0);
            acc[1][nt] = __builtin_amdgcn_mfma_f32_16x16x32_bf16(a1, bb, acc[1][nt], 0, 0, 0);
        }
    }

    // epilogue: bias, scale by rsqrt(deg+1), bf16 store
#pragma unroll
    for (int mt = 0; mt < 2; ++mt) {
#pragma unroll
        for (int r = 0; r < 4; ++r) {
            int row = row0 + wv * 32 + mt * 16 + quad * 4 + r;
            if (row >= n) continue;
            float rsw = rsqrtf((float)(cnt[(size_t)row * CNT_STRIDE] + 1));
#pragma unroll
            for (int nt = 0; nt < 8; ++nt) {
                int col = nt * 16 + l16;
                hsb[(size_t)row * 128 + col] = f2bf((acc[mt][nt][r] + b[col]) * rsw);
            }
        }
    }
}

// Half-wave (32 lanes) per node; lane = 4 channels (ushort4 = 8B).
// out[d] = rs_d * ( g[d] + sum_{s in N(d)} g[s] ),  g = rs*hs (from k_gemm).
__global__ __launch_bounds__(256) void k_agg(const int* __restrict__ cnt,
                                             const unsigned short* __restrict__ ell,
                                             const int2* __restrict__ ovf,
                                             const unsigned short* __restrict__ hsb,
                                             float* __restrict__ out, int n) {
    int node = blockIdx.x * 8 + (threadIdx.x >> 5);
    if (node >= n) return;
    int lane = threadIdx.x & 31;
    int deg = cnt[(size_t)node * CNT_STRIDE];
    float rsn = rsqrtf((float)(deg + 1));
    int m = min(deg, CAP);

    const ushort4* hp = (const ushort4*)hsb;  // row = 32 ushort4
    ushort4 sv = hp[(size_t)node * 32 + lane];
    float4 acc;
    acc.x = bf2f(sv.x); acc.y = bf2f(sv.y);
    acc.z = bf2f(sv.z); acc.w = bf2f(sv.w);

    const unsigned short* row = ell + (size_t)node * CAP;  // 80B/node, 16B-aligned
    int e = 0;
    for (; e + 8 <= m; e += 8) {  // one 16B index load + 8 row gathers in flight
        us8 p = *(const us8*)(row + e);
        ushort4 v0 = hp[(size_t)p[0] * 32 + lane];
        ushort4 v1 = hp[(size_t)p[1] * 32 + lane];
        ushort4 v2 = hp[(size_t)p[2] * 32 + lane];
        ushort4 v3 = hp[(size_t)p[3] * 32 + lane];
        ushort4 v4 = hp[(size_t)p[4] * 32 + lane];
        ushort4 v5 = hp[(size_t)p[5] * 32 + lane];
        ushort4 v6 = hp[(size_t)p[6] * 32 + lane];
        ushort4 v7 = hp[(size_t)p[7] * 32 + lane];
        acca(acc, v0); acca(acc, v1); acca(acc, v2); acca(acc, v3);
        acca(acc, v4); acca(acc, v5); acca(acc, v6); acca(acc, v7);
    }
    if (e + 4 <= m) {
        us4 p = *(const us4*)(row + e);
        ushort4 v0 = hp[(size_t)p[0] * 32 + lane];
        ushort4 v1 = hp[(size_t)p[1] * 32 + lane];
        ushort4 v2 = hp[(size_t)p[2] * 32 + lane];
        ushort4 v3 = hp[(size_t)p[3] * 32 + lane];
        acca(acc, v0); acca(acc, v1); acca(acc, v2); acca(acc, v3);
        e += 4;
    }
    for (; e < m; ++e) {
        ushort4 v = hp[(size_t)row[e] * 32 + lane];
        acca(acc, v);
    }
    if (deg > CAP) {  // expect: never taken (P ~ 3e-7 per node)
        int novf = cnt[(size_t)n * CNT_STRIDE];
        for (int i = 0; i < novf; ++i) {
            int2 p = ovf[i];
            if (p.y == node) {
                ushort4 v = hp[(size_t)p.x * 32 + lane];
                acca(acc, v);
            }
        }
    }
    acc.x *= rsn; acc.y *= rsn; acc.z *= rsn; acc.w *= rsn;
    ((float4*)out)[(size_t)node * 32 + lane] = acc;
}

extern "C" void kernel_launch(void* const* d_in, const int* in_sizes, int n_in,
                              void* d_out, int out_size, void* d_ws, size_t ws_size,
                              hipStream_t stream) {
    const float* h = (const float*)d_in[0];
    const float* W = (const float*)d_in[1];
    const float* b = (const float*)d_in[2];
    const int* edges = (const int*)d_in[3];

    const int n = in_sizes[0] / IN_DIM;  // 50000  (ushort ELL assumes n < 65536)
    const int E = in_sizes[3] / 2;       // 800000
    const int nlin = (n + 127) / 128;    // 391 GEMM tiles

    // workspace carve-up (float units, each region 2KB-aligned)
    size_t o = 0;
    auto carve = [&](size_t elems) {
        size_t cur = o;
        o += (elems + 511) & ~(size_t)511;
        return cur;
    };
    float* ws = (float*)d_ws;
    unsigned short* hsb = (unsigned short*)(ws + carve((size_t)n * 64));          // n*128 bf16
    int* cnt = (int*)(ws + carve((size_t)(n + 1) * CNT_STRIDE));                  // padded counters
    unsigned short* ell = (unsigned short*)(ws + carve((size_t)n * CAP / 2 + 64));// n*CAP ushort
    int2* ovf = (int2*)(ws + carve((size_t)E * 2));

    float* out = (float*)d_out;

    hipMemsetAsync(cnt, 0, (size_t)(n + 1) * CNT_STRIDE * sizeof(int), stream);
    k_fill<<<(E + 255) / 256, 256, 0, stream>>>(edges, cnt, ell, ovf, E, n);
    k_gemm<<<nlin, 256, 0, stream>>>(h, W, b, cnt, hsb, n);
    k_agg<<<(n + 7) / 8, 256, 0, stream>>>(cnt, ell, ovf, hsb, out, n);
}

// Round 4
// 150.742 us; speedup vs baseline: 1.1933x; 1.1583x over previous
//
#include <hip/hip_runtime.h>

// GCN layer: out = A_norm @ (h @ W^T + b), A_norm = D^-1/2 (A + I) D^-1/2
// Inputs: h [N,128] f32, W [128,128] f32, b [128] f32, edges [2,E] int32
// Output: [N,128] f32
//
// R13: replace the 55us scatter-fill (one partial-line HBM writeback per
//      edge: WRITE_SIZE 48.9MB = 800K x 61B) with a two-pass LDS counting
//      sort:
//        k_binA: 256 blocks x 3125 edges; LDS ticket per dst-bin (dst>>8,
//                196 bins); packed rec src|dstlo<<16 into private
//                per-(block,bin) region (31KB/block, L2-resident).
//        k_binB: one block per bin; prefix-scan the 256 counts, re-expand,
//                build ELL rows in LDS (LDS atomics = true degree), write
//                ELL + cnt as coalesced full lines.
//      Device atomics 800K -> ~0 (overflow paths only). cnt unpadded.
//      Pipeline: memset(8B) -> k_binA -> k_binB -> k_gemm -> k_agg.

#define IN_DIM 128
#define OUT_DIM 128
#define CAP 40    // ELL capacity/node; P(deg>40 | Poisson(16)) ~ 3e-7
#define NB_A 256  // pass-A blocks (= per-bin count rows in pass B)
#define NBIN 196  // ceil(50176/256) dst bins, 256 nodes each
#define BINW 256  // nodes per bin
#define CAPA 44   // per-(block,bin) record capacity; lambda=15.9, P(>44)~1e-9
#define OVCAP 4096

typedef short bf16x8 __attribute__((ext_vector_type(8)));
typedef float f32x4 __attribute__((ext_vector_type(4)));
typedef unsigned short us8 __attribute__((ext_vector_type(8)));
typedef unsigned short us4 __attribute__((ext_vector_type(4)));

__device__ __forceinline__ unsigned short f2bf(float f) {
    unsigned u = __float_as_uint(f);
    u += 0x7fffu + ((u >> 16) & 1u);  // round-nearest-even
    return (unsigned short)(u >> 16);
}
__device__ __forceinline__ float bf2f(unsigned short s) {
    return __uint_as_float(((unsigned)s) << 16);
}
__device__ __forceinline__ void acca(float4& acc, ushort4 v) {
    acc.x += bf2f(v.x);
    acc.y += bf2f(v.y);
    acc.z += bf2f(v.z);
    acc.w += bf2f(v.w);
}

// ---- pass A: bin edges by dst>>8 into private per-(block,bin) regions ----
__global__ __launch_bounds__(256) void k_binA(const int* __restrict__ ed,
                                              unsigned* __restrict__ gbuf,
                                              int* __restrict__ gcnt,
                                              int2* __restrict__ aov,
                                              int* __restrict__ aovc, int E) {
    __shared__ int bc[NBIN];
    const int tid = threadIdx.x;
    const int blk = blockIdx.x;
    for (int i = tid; i < NBIN; i += 256) bc[i] = 0;
    __syncthreads();
    const int chunk = (E + NB_A - 1) / NB_A;
    const int e0 = blk * chunk, e1 = min(E, e0 + chunk);
    for (int e = e0 + tid; e < e1; e += 256) {
        int s = ed[e];
        int d = ed[E + e];
        int bin = d >> 8, lo = d & 255;
        int r = atomicAdd(&bc[bin], 1);  // LDS atomic
        if (r < CAPA) {
            gbuf[((size_t)blk * NBIN + bin) * CAPA + r] = (unsigned)s | ((unsigned)lo << 16);
        } else {
            int k = atomicAdd(aovc, 1);
            if (k < OVCAP) aov[k] = make_int2(s, d);
        }
    }
    __syncthreads();
    for (int i = tid; i < NBIN; i += 256) gcnt[blk * NBIN + i] = min(bc[i], CAPA);
}

// ---- pass B: one block per bin; build ELL rows for 256 nodes in LDS ----
__global__ __launch_bounds__(256) void k_binB(const unsigned* __restrict__ gbuf,
                                              const int* __restrict__ gcnt,
                                              const int2* __restrict__ aov,
                                              const int* __restrict__ aovc,
                                              unsigned short* __restrict__ ell,
                                              int* __restrict__ cnt,
                                              int2* __restrict__ ovf2,
                                              int* __restrict__ ovf2c, int n) {
    __shared__ int pfx[NB_A + 1];
    __shared__ int lcnt[BINW];
    __shared__ int ws4[4];
    __shared__ __align__(16) unsigned short ells[BINW * CAP];  // 20 KB
    const int tid = threadIdx.x;
    const int bin = blockIdx.x;
    const int node0 = bin << 8;
    const int lane = tid & 63;
    const int wv = tid >> 6;

    lcnt[tid] = 0;
    // load per-pass-A-block counts for this bin and exclusive-scan them
    int c = gcnt[tid * NBIN + bin];
    int x = c;
#pragma unroll
    for (int d = 1; d < 64; d <<= 1) {
        int t = __shfl_up(x, d, 64);
        if (lane >= d) x += t;
    }
    if (lane == 63) ws4[wv] = x;
    __syncthreads();
    if (tid == 0) {
        int a = 0;
#pragma unroll
        for (int j = 0; j < 4; ++j) { int t = ws4[j]; ws4[j] = a; a += t; }
    }
    __syncthreads();
    pfx[tid + 1] = ws4[wv] + x;  // inclusive prefix
    if (tid == 0) pfx[0] = 0;
    __syncthreads();
    const int total = pfx[NB_A];

    for (int base = 0; base < total; base += 256) {
        int idx = base + tid;
        if (idx < total) {
            // find blk: largest b with pfx[b] <= idx
            int lo = 0, hi = NB_A;
            while (hi - lo > 1) {
                int mid = (lo + hi) >> 1;
                if (pfx[mid] <= idx) lo = mid; else hi = mid;
            }
            int slot = idx - pfx[lo];
            unsigned rec = gbuf[((size_t)lo * NBIN + bin) * CAPA + slot];
            int src = rec & 0xffff;
            int dlo = rec >> 16;
            int r = atomicAdd(&lcnt[dlo], 1);  // LDS atomic; counts true degree
            if (r < CAP) {
                ells[dlo * CAP + r] = (unsigned short)src;
            } else {
                int k = atomicAdd(ovf2c, 1);
                if (k < OVCAP) ovf2[k] = make_int2(src, node0 + dlo);
            }
        }
    }
    // merge pass-A overflow edges belonging to this bin (rare/never)
    int nov = min(*aovc, OVCAP);
    for (int i = tid; i < nov; i += 256) {
        int2 p = aov[i];
        if ((p.y >> 8) == bin) {
            int dlo = p.y & 255;
            int r = atomicAdd(&lcnt[dlo], 1);
            if (r < CAP) {
                ells[dlo * CAP + r] = (unsigned short)p.x;
            } else {
                int k = atomicAdd(ovf2c, 1);
                if (k < OVCAP) ovf2[k] = make_int2(p.x, p.y);
            }
        }
    }
    __syncthreads();
    // coalesced write-out: degrees + 20KB of ELL rows
    int node = node0 + tid;
    if (node < n) cnt[node] = lcnt[tid];
    const int4* sp = (const int4*)ells;
    int4* dp = (int4*)(ell + (size_t)node0 * CAP);
#pragma unroll
    for (int i = tid; i < BINW * CAP * 2 / 16; i += 256) dp[i] = sp[i];
}

// MFMA linear: hs[row] = bf16( (h@W^T + b)[row] * rsqrt(deg[row]+1) ).
__global__ __launch_bounds__(256) void k_gemm(
        const float* __restrict__ h, const float* __restrict__ W,
        const float* __restrict__ b, const int* __restrict__ cnt,
        unsigned short* __restrict__ hsb, int n) {
    __shared__ unsigned short sA[128 * 136];  // h tile bf16 (+8 pad)
    __shared__ unsigned short sB[128 * 136];  // W bf16 [n][k]

    const int tid = threadIdx.x;
    const int lane = tid & 63;
    const int wv = tid >> 6;
    const int quad = lane >> 4;
    const int l16 = lane & 15;
    const int row0 = blockIdx.x * 128;

    {
        const float4* h4 = (const float4*)h;
        const float4* W4 = (const float4*)W;
        for (int t = tid; t < 128 * 32; t += 256) {
            int r = t >> 5, c4 = t & 31;
            int row = row0 + r;
            float4 v = make_float4(0.f, 0.f, 0.f, 0.f);
            if (row < n) v = h4[(size_t)row * 32 + c4];
            ushort4 p;
            p.x = f2bf(v.x); p.y = f2bf(v.y); p.z = f2bf(v.z); p.w = f2bf(v.w);
            ((ushort4*)sA)[r * 34 + c4] = p;  // 136/4 = 34
            float4 w = W4[t];
            ushort4 q;
            q.x = f2bf(w.x); q.y = f2bf(w.y); q.z = f2bf(w.z); q.w = f2bf(w.w);
            ((ushort4*)sB)[r * 34 + c4] = q;
        }
    }
    __syncthreads();

    f32x4 acc[2][8];
#pragma unroll
    for (int mt = 0; mt < 2; ++mt)
#pragma unroll
        for (int nt = 0; nt < 8; ++nt) acc[mt][nt] = (f32x4){0.f, 0.f, 0.f, 0.f};

    const int koff = quad * 8;
#pragma unroll
    for (int kc = 0; kc < 4; ++kc) {
        int kbase = kc * 32 + koff;
        bf16x8 a0 = *(const bf16x8*)(sA + (wv * 32 + 0 + l16) * 136 + kbase);
        bf16x8 a1 = *(const bf16x8*)(sA + (wv * 32 + 16 + l16) * 136 + kbase);
#pragma unroll
        for (int nt = 0; nt < 8; ++nt) {
            bf16x8 bb = *(const bf16x8*)(sB + (nt * 16 + l16) * 136 + kbase);
            acc[0][nt] = __builtin_amdgcn_mfma_f32_16x16x32_bf16(a0, bb, acc[0][nt], 0, 0, 0);
            acc[1][nt] = __builtin_amdgcn_mfma_f32_16x16x32_bf16(a1, bb, acc[1][nt], 0, 0, 0);
        }
    }

    // epilogue: bias, scale by rsqrt(deg+1), bf16 store
#pragma unroll
    for (int mt = 0; mt < 2; ++mt) {
#pragma unroll
        for (int r = 0; r < 4; ++r) {
            int row = row0 + wv * 32 + mt * 16 + quad * 4 + r;
            if (row >= n) continue;
            float rsw = rsqrtf((float)(cnt[row] + 1));
#pragma unroll
            for (int nt = 0; nt < 8; ++nt) {
                int col = nt * 16 + l16;
                hsb[(size_t)row * 128 + col] = f2bf((acc[mt][nt][r] + b[col]) * rsw);
            }
        }
    }
}

// Half-wave (32 lanes) per node; lane = 4 channels (ushort4 = 8B).
// out[d] = rs_d * ( g[d] + sum_{s in N(d)} g[s] ),  g = rs*hs (from k_gemm).
__global__ __launch_bounds__(256) void k_agg(const int* __restrict__ cnt,
                                             const unsigned short* __restrict__ ell,
                                             const int2* __restrict__ ovf2,
                                             const int* __restrict__ ovf2c,
                                             const unsigned short* __restrict__ hsb,
                                             float* __restrict__ out, int n) {
    int node = blockIdx.x * 8 + (threadIdx.x >> 5);
    if (node >= n) return;
    int lane = threadIdx.x & 31;
    int deg = cnt[node];
    float rsn = rsqrtf((float)(deg + 1));
    int m = min(deg, CAP);

    const ushort4* hp = (const ushort4*)hsb;  // row = 32 ushort4
    ushort4 sv = hp[(size_t)node * 32 + lane];
    float4 acc;
    acc.x = bf2f(sv.x); acc.y = bf2f(sv.y);
    acc.z = bf2f(sv.z); acc.w = bf2f(sv.w);

    const unsigned short* row = ell + (size_t)node * CAP;  // 80B/node, 16B-aligned
    int e = 0;
    for (; e + 8 <= m; e += 8) {  // one 16B index load + 8 row gathers in flight
        us8 p = *(const us8*)(row + e);
        ushort4 v0 = hp[(size_t)p[0] * 32 + lane];
        ushort4 v1 = hp[(size_t)p[1] * 32 + lane];
        ushort4 v2 = hp[(size_t)p[2] * 32 + lane];
        ushort4 v3 = hp[(size_t)p[3] * 32 + lane];
        ushort4 v4 = hp[(size_t)p[4] * 32 + lane];
        ushort4 v5 = hp[(size_t)p[5] * 32 + lane];
        ushort4 v6 = hp[(size_t)p[6] * 32 + lane];
        ushort4 v7 = hp[(size_t)p[7] * 32 + lane];
        acca(acc, v0); acca(acc, v1); acca(acc, v2); acca(acc, v3);
        acca(acc, v4); acca(acc, v5); acca(acc, v6); acca(acc, v7);
    }
    if (e + 4 <= m) {
        us4 p = *(const us4*)(row + e);
        ushort4 v0 = hp[(size_t)p[0] * 32 + lane];
        ushort4 v1 = hp[(size_t)p[1] * 32 + lane];
        ushort4 v2 = hp[(size_t)p[2] * 32 + lane];
        ushort4 v3 = hp[(size_t)p[3] * 32 + lane];
        acca(acc, v0); acca(acc, v1); acca(acc, v2); acca(acc, v3);
        e += 4;
    }
    for (; e < m; ++e) {
        ushort4 v = hp[(size_t)row[e] * 32 + lane];
        acca(acc, v);
    }
    if (deg > CAP) {  // expect: never taken (P ~ 3e-7 per node)
        int novf = min(*ovf2c, OVCAP);
        for (int i = 0; i < novf; ++i) {
            int2 p = ovf2[i];
            if (p.y == node) {
                ushort4 v = hp[(size_t)p.x * 32 + lane];
                acca(acc, v);
            }
        }
    }
    acc.x *= rsn; acc.y *= rsn; acc.z *= rsn; acc.w *= rsn;
    ((float4*)out)[(size_t)node * 32 + lane] = acc;
}

extern "C" void kernel_launch(void* const* d_in, const int* in_sizes, int n_in,
                              void* d_out, int out_size, void* d_ws, size_t ws_size,
                              hipStream_t stream) {
    const float* h = (const float*)d_in[0];
    const float* W = (const float*)d_in[1];
    const float* b = (const float*)d_in[2];
    const int* edges = (const int*)d_in[3];

    const int n = in_sizes[0] / IN_DIM;  // 50000  (ushort ELL assumes n < 65536)
    const int E = in_sizes[3] / 2;       // 800000
    const int nlin = (n + 127) / 128;    // 391 GEMM tiles
    const int nnode_pad = NBIN * BINW;   // 50176

    // workspace carve-up (float units, each region 2KB-aligned)
    size_t o = 0;
    auto carve = [&](size_t elems) {
        size_t cur = o;
        o += (elems + 511) & ~(size_t)511;
        return cur;
    };
    float* ws = (float*)d_ws;
    unsigned short* hsb = (unsigned short*)(ws + carve((size_t)n * 64));        // n*128 bf16
    int* cnt = (int*)(ws + carve(nnode_pad));                                   // degrees
    unsigned short* ell = (unsigned short*)(ws + carve((size_t)nnode_pad * CAP / 2)); // padded-node ELL
    unsigned* gbuf = (unsigned*)(ws + carve((size_t)NB_A * NBIN * CAPA));       // 8.8 MB bins
    int* gcnt = (int*)(ws + carve((size_t)NB_A * NBIN));
    int2* aov = (int2*)(ws + carve(OVCAP * 2));
    int2* ovf2 = (int2*)(ws + carve(OVCAP * 2));
    int* ctrs = (int*)(ws + carve(2));  // [0]=aovc, [1]=ovf2c

    float* out = (float*)d_out;

    hipMemsetAsync(ctrs, 0, 2 * sizeof(int), stream);
    k_binA<<<NB_A, 256, 0, stream>>>(edges, gbuf, gcnt, aov, ctrs + 0, E);
    k_binB<<<NBIN, 256, 0, stream>>>(gbuf, gcnt, aov, ctrs + 0, ell, cnt, ovf2, ctrs + 1, n);
    k_gemm<<<nlin, 256, 0, stream>>>(h, W, b, cnt, hsb, n);
    k_agg<<<(n + 7) / 8, 256, 0, stream>>>(cnt, ell, ovf2, ctrs + 1, hsb, out, n);
}